// Round 7
// baseline (947.278 us; speedup 1.0000x reference)
//
#include <hip/hip_runtime.h>
#include <hip/hip_bf16.h>

#define T 2048
#define C 4096
#define H 32
#define KVH 8
#define D 128
// rep = H/KVH = 4

typedef __bf16 bf16x8 __attribute__((ext_vector_type(8)));
typedef __bf16 bf16x4 __attribute__((ext_vector_type(4)));
typedef float floatx4 __attribute__((ext_vector_type(4)));

#define MFMA16 __builtin_amdgcn_mfma_f32_16x16x32_bf16

// ---------------- split-bf16 MFMA GEMM, 3-term compute body ----------------
// acc = A @ B with A,B fp32 decomposed on the fly to hi+lo bf16; product =
// hh + lh + hl (~2^-17 rel). 128x128 tile, BK=32, 4 waves (2x2), each wave
// 4x4 frags of 16x16x32 MFMA. Column map per wave: bcol(ni) =
// wn*32 + (ni&1)*16 + (ni>>1)*64 + n16 -- puts the RoPE pair (d, d+64) in
// the SAME thread (ni and ni+2), enabling the fused k-rope epilogue.
// NOTE (round-5 post-mortem): NO min-waves arg on __launch_bounds__ (capped
// unified VGPR/AGPR at 128 -> VGPR_Count 56, MfmaUtil 11%, 505us).
// NOTE (round-4 post-mortem): ONE LDS allocation per kernel; per-instantiation
// __shared__ arrays doubled LDS to 70KB and halved residency.
__device__ __forceinline__ void qkv_compute3(
    const float* __restrict__ A, const float* __restrict__ B,
    int N, int row0, int col0,
    __bf16 (&Ah)[128][40], __bf16 (&Al)[128][40],
    __bf16 (&Bh)[128][40], __bf16 (&Bl)[128][40],
    floatx4 (&acc)[4][4]) {
  const int tid = threadIdx.x;
  const int lane = tid & 63;
  const int w = tid >> 6;
  const int n16 = lane & 15;
  const int quad = lane >> 4;
  const int wm = w >> 1, wn = w & 1;
  const int ar = tid >> 3;        // A row within 32-row group
  const int ak = (tid & 7) * 4;   // A k-quad
  const int bg = tid >> 7;        // B k-group (0..1)
  const int bn = tid & 127;       // B col within tile

  int bcol[4];
#pragma unroll
  for (int ni = 0; ni < 4; ++ni)
    bcol[ni] = wn * 32 + (ni & 1) * 16 + (ni >> 1) * 64 + n16;

  for (int k0 = 0; k0 < C; k0 += 32) {
#pragma unroll
    for (int p = 0; p < 4; ++p) {
      const int r = p * 32 + ar;
      const float4 av = *(const float4*)(A + (size_t)(row0 + r) * C + k0 + ak);
      bf16x4 h, l;
      h[0] = (__bf16)av.x; l[0] = (__bf16)(av.x - (float)h[0]);
      h[1] = (__bf16)av.y; l[1] = (__bf16)(av.y - (float)h[1]);
      h[2] = (__bf16)av.z; l[2] = (__bf16)(av.z - (float)h[2]);
      h[3] = (__bf16)av.w; l[3] = (__bf16)(av.w - (float)h[3]);
      *(bf16x4*)(&Ah[r][ak]) = h;
      *(bf16x4*)(&Al[r][ak]) = l;
    }
#pragma unroll
    for (int p = 0; p < 4; ++p) {
      const int kb = bg * 16 + p * 4;
      const float* bp = B + (size_t)(k0 + kb) * N + col0 + bn;
      const float f0 = bp[0];
      const float f1 = bp[(size_t)N];
      const float f2 = bp[(size_t)2 * N];
      const float f3 = bp[(size_t)3 * N];
      bf16x4 h, l;
      h[0] = (__bf16)f0; l[0] = (__bf16)(f0 - (float)h[0]);
      h[1] = (__bf16)f1; l[1] = (__bf16)(f1 - (float)h[1]);
      h[2] = (__bf16)f2; l[2] = (__bf16)(f2 - (float)h[2]);
      h[3] = (__bf16)f3; l[3] = (__bf16)(f3 - (float)h[3]);
      *(bf16x4*)(&Bh[bn][kb]) = h;
      *(bf16x4*)(&Bl[bn][kb]) = l;
    }
    __syncthreads();
    bf16x8 a_h[4], a_l[4], b_h[4], b_l[4];
#pragma unroll
    for (int mi = 0; mi < 4; ++mi) {
      a_h[mi] = *(const bf16x8*)(&Ah[wm * 64 + mi * 16 + n16][quad * 8]);
      a_l[mi] = *(const bf16x8*)(&Al[wm * 64 + mi * 16 + n16][quad * 8]);
    }
#pragma unroll
    for (int ni = 0; ni < 4; ++ni) {
      b_h[ni] = *(const bf16x8*)(&Bh[bcol[ni]][quad * 8]);
      b_l[ni] = *(const bf16x8*)(&Bl[bcol[ni]][quad * 8]);
    }
#pragma unroll
    for (int mi = 0; mi < 4; ++mi)
#pragma unroll
      for (int ni = 0; ni < 4; ++ni) {
        acc[mi][ni] = MFMA16(a_h[mi], b_h[ni], acc[mi][ni], 0, 0, 0);
        acc[mi][ni] = MFMA16(a_l[mi], b_h[ni], acc[mi][ni], 0, 0, 0);
        acc[mi][ni] = MFMA16(a_h[mi], b_l[ni], acc[mi][ni], 0, 0, 0);
      }
    __syncthreads();
  }
}

// Fused Q/K/V projections + conversions, one 768-block launch, 3 epilogues:
//   bx<32 : q -> q_ws fp32 (flash_attn applies rope at load)
//   bx<40 : k -> rope in epilogue -> out_k fp32 + khi/klo bf16 [kvh][t][d]
//   else  : v -> out_v fp32 [kvh][t][d] + vt bf16 [kvh][d][t] (LDS transpose)
__global__ __launch_bounds__(256) void gemm_qkv(
    const float* __restrict__ x, const float* __restrict__ Wq,
    const float* __restrict__ Wk, const float* __restrict__ Wv,
    float* __restrict__ q_ws, float* __restrict__ out_k,
    __bf16* __restrict__ khi, __bf16* __restrict__ klo,
    float* __restrict__ out_v, __bf16* __restrict__ vt,
    const float* __restrict__ cosb, const float* __restrict__ sinb) {
  __shared__ __bf16 Ah[128][40], Al[128][40], Bh[128][40], Bl[128][40];
  const int bx = blockIdx.x;
  const int row0 = blockIdx.y * 128;
  const float* B;
  int N, col0, mode;
  if (bx < 32)      { B = Wq; N = H * D;   col0 = bx * 128;        mode = 0; }
  else if (bx < 40) { B = Wk; N = KVH * D; col0 = (bx - 32) * 128; mode = 1; }
  else              { B = Wv; N = KVH * D; col0 = (bx - 40) * 128; mode = 2; }

  floatx4 acc[4][4];
#pragma unroll
  for (int mi = 0; mi < 4; ++mi)
#pragma unroll
    for (int ni = 0; ni < 4; ++ni) acc[mi][ni] = (floatx4){0.f, 0.f, 0.f, 0.f};

  qkv_compute3(x, B, N, row0, col0, Ah, Al, Bh, Bl, acc);

  const int lane = threadIdx.x & 63;
  const int w = threadIdx.x >> 6;
  const int n16 = lane & 15;
  const int quad = lane >> 4;
  const int wm = w >> 1, wn = w & 1;
  int bcol[4];
#pragma unroll
  for (int ni = 0; ni < 4; ++ni)
    bcol[ni] = wn * 32 + (ni & 1) * 16 + (ni >> 1) * 64 + n16;

  if (mode == 0) {
    // ---- q epilogue: plain fp32 store ----
#pragma unroll
    for (int mi = 0; mi < 4; ++mi)
#pragma unroll
      for (int i = 0; i < 4; ++i) {
        const int r = row0 + wm * 64 + mi * 16 + quad * 4 + i;
        float* cp = q_ws + (size_t)r * (H * D) + col0;
#pragma unroll
        for (int ni = 0; ni < 4; ++ni) cp[bcol[ni]] = acc[mi][ni][i];
      }
  } else if (mode == 1) {
    // ---- k epilogue: rope pair (ni, ni+2) thread-local; cos[t][d+64]==cos[t][d]
    const int kvh = col0 >> 7;
#pragma unroll
    for (int mi = 0; mi < 4; ++mi)
#pragma unroll
      for (int i = 0; i < 4; ++i) {
        const int t = row0 + wm * 64 + mi * 16 + quad * 4 + i;
#pragma unroll
        for (int ni = 0; ni < 2; ++ni) {
          const int dlo = bcol[ni];          // in [0,64)
          const float cv = cosb[(size_t)t * D + dlo];
          const float sv = sinb[(size_t)t * D + dlo];
          const float a = acc[mi][ni][i];
          const float b = acc[mi][ni + 2][i];
          const float r1 = a * cv - b * sv;
          const float r2 = b * cv + a * sv;
          const size_t base = ((size_t)kvh * T + t) * D + dlo;
          out_k[base] = r1;
          out_k[base + 64] = r2;
          const __bf16 h1 = (__bf16)r1;
          khi[base] = h1;
          klo[base] = (__bf16)(r1 - (float)h1);
          const __bf16 h2 = (__bf16)r2;
          khi[base + 64] = h2;
          klo[base + 64] = (__bf16)(r2 - (float)h2);
        }
      }
  } else {
    // ---- v epilogue: fp32 out_v direct; bf16 transpose via LDS reuse ----
    const int kvh = col0 >> 7;
#pragma unroll
    for (int mi = 0; mi < 4; ++mi)
#pragma unroll
      for (int i = 0; i < 4; ++i) {
        const int r = row0 + wm * 64 + mi * 16 + quad * 4 + i;
        float* cp = out_v + ((size_t)kvh * T + r) * D;
#pragma unroll
        for (int ni = 0; ni < 4; ++ni) cp[bcol[ni]] = acc[mi][ni][i];
      }
    // reuse the 40KB GEMM LDS as a [128][129] bf16 tile (33 KB; stride 258B
    // makes the strided read side ~2-way bank aliasing). K-loop ended with
    // __syncthreads -> safe to overwrite.
    __bf16 (*tile)[129] = (__bf16(*)[129])(&Ah[0][0]);
#pragma unroll
    for (int mi = 0; mi < 4; ++mi)
#pragma unroll
      for (int i = 0; i < 4; ++i) {
        const int tl = wm * 64 + mi * 16 + quad * 4 + i;
#pragma unroll
        for (int ni = 0; ni < 4; ++ni)
          tile[tl][bcol[ni]] = (__bf16)acc[mi][ni][i];
      }
    __syncthreads();
#pragma unroll
    for (int p = 0; p < 8; ++p) {
      const int idx = p * 256 + threadIdx.x;   // [0, 2048)
      const int d = idx >> 4;                  // [0, 128)
      const int t0l = (idx & 15) * 8;
      bf16x8 v8;
#pragma unroll
      for (int j = 0; j < 8; ++j) v8[j] = tile[t0l + j][d];
      *(bf16x8*)(vt + ((size_t)kvh * D + d) * T + row0 + t0l) = v8;
    }
  }
}

// ---------------- Wo projection: self-contained 2-term GEMM ----------------
// B plain bf16 (~2^-9 rel on B only; fine for the linear y path).
__global__ __launch_bounds__(256) void gemm_wo(
    const float* __restrict__ A, const float* __restrict__ B,
    float* __restrict__ Cm) {
  __shared__ __bf16 Ah[128][40], Al[128][40], Bh[128][40];
  const int N = C;
  const int row0 = blockIdx.y * 128;
  const int col0 = blockIdx.x * 128;
  const int tid = threadIdx.x;
  const int lane = tid & 63;
  const int w = tid >> 6;
  const int n16 = lane & 15;
  const int quad = lane >> 4;
  const int wm = w >> 1, wn = w & 1;

  floatx4 acc[4][4];
#pragma unroll
  for (int mi = 0; mi < 4; ++mi)
#pragma unroll
    for (int ni = 0; ni < 4; ++ni) acc[mi][ni] = (floatx4){0.f, 0.f, 0.f, 0.f};

  const int ar = tid >> 3;
  const int ak = (tid & 7) * 4;
  const int bg = tid >> 7;
  const int bn = tid & 127;

  for (int k0 = 0; k0 < C; k0 += 32) {
#pragma unroll
    for (int p = 0; p < 4; ++p) {
      const int r = p * 32 + ar;
      const float4 av = *(const float4*)(A + (size_t)(row0 + r) * C + k0 + ak);
      bf16x4 h, l;
      h[0] = (__bf16)av.x; l[0] = (__bf16)(av.x - (float)h[0]);
      h[1] = (__bf16)av.y; l[1] = (__bf16)(av.y - (float)h[1]);
      h[2] = (__bf16)av.z; l[2] = (__bf16)(av.z - (float)h[2]);
      h[3] = (__bf16)av.w; l[3] = (__bf16)(av.w - (float)h[3]);
      *(bf16x4*)(&Ah[r][ak]) = h;
      *(bf16x4*)(&Al[r][ak]) = l;
    }
#pragma unroll
    for (int p = 0; p < 4; ++p) {
      const int kb = bg * 16 + p * 4;
      const float* bp = B + (size_t)(k0 + kb) * N + col0 + bn;
      bf16x4 h;
      h[0] = (__bf16)bp[0];
      h[1] = (__bf16)bp[(size_t)N];
      h[2] = (__bf16)bp[(size_t)2 * N];
      h[3] = (__bf16)bp[(size_t)3 * N];
      *(bf16x4*)(&Bh[bn][kb]) = h;
    }
    __syncthreads();
    bf16x8 a_h[4], a_l[4], b_h[4];
#pragma unroll
    for (int mi = 0; mi < 4; ++mi) {
      a_h[mi] = *(const bf16x8*)(&Ah[wm * 64 + mi * 16 + n16][quad * 8]);
      a_l[mi] = *(const bf16x8*)(&Al[wm * 64 + mi * 16 + n16][quad * 8]);
    }
#pragma unroll
    for (int ni = 0; ni < 4; ++ni)
      b_h[ni] = *(const bf16x8*)(&Bh[wn * 64 + ni * 16 + n16][quad * 8]);
#pragma unroll
    for (int mi = 0; mi < 4; ++mi)
#pragma unroll
      for (int ni = 0; ni < 4; ++ni) {
        acc[mi][ni] = MFMA16(a_h[mi], b_h[ni], acc[mi][ni], 0, 0, 0);
        acc[mi][ni] = MFMA16(a_l[mi], b_h[ni], acc[mi][ni], 0, 0, 0);
      }
    __syncthreads();
  }
#pragma unroll
  for (int mi = 0; mi < 4; ++mi)
#pragma unroll
    for (int i = 0; i < 4; ++i) {
      const int r = row0 + wm * 64 + mi * 16 + quad * 4 + i;
      float* cp = Cm + (size_t)r * N + col0 + wn * 64 + n16;
#pragma unroll
      for (int ni = 0; ni < 4; ++ni) cp[ni * 16] = acc[mi][ni][i];
    }
}

// ---------------- MFMA flash attention, balanced + LDS-staged --------------
// Grid (T/128, H); block bx owns Q-blocks p_lo=bx and p_hi=31-bx (light+heavy
// pairing -> uniform per-block compute). 4 waves; wave w owns 16-row strips
// of BOTH Q-blocks. Per KV step the whole block cooperatively stages K(hi+lo)
// and V tiles into double-buffered LDS (issue loads for t+1 before compute of
// t, ds_write after, ONE barrier per tile). RoPE applied to Q at load time.
// NOTE (round-3 post-mortem): defer-max + setprio here caused accumulator
// regalloc collapse -> ~1 GB scratch spill traffic. Keep softmax straight-line.
struct StageRegs { bf16x8 k0, k1, l0, l1, v0, v1; };

__device__ __forceinline__ void stage_load(
    StageRegs& s, const __bf16* __restrict__ Kh, const __bf16* __restrict__ Kl,
    const __bf16* __restrict__ Vt, int j0, int tid) {
  const int kr = tid >> 4, kj = (tid & 15) * 8;
  s.k0 = *(const bf16x8*)(Kh + (size_t)(j0 + kr) * D + kj);
  s.k1 = *(const bf16x8*)(Kh + (size_t)(j0 + kr + 16) * D + kj);
  s.l0 = *(const bf16x8*)(Kl + (size_t)(j0 + kr) * D + kj);
  s.l1 = *(const bf16x8*)(Kl + (size_t)(j0 + kr + 16) * D + kj);
  const int vd = tid >> 2, vj = (tid & 3) * 8;
  s.v0 = *(const bf16x8*)(Vt + (size_t)vd * T + j0 + vj);
  s.v1 = *(const bf16x8*)(Vt + (size_t)(vd + 64) * T + j0 + vj);
}

__device__ __forceinline__ void stage_write(
    const StageRegs& s, __bf16* __restrict__ KhL, __bf16* __restrict__ KlL,
    __bf16* __restrict__ VL, int tid) {
  const int kr = tid >> 4, kj = (tid & 15) * 8;
  *(bf16x8*)(KhL + kr * 136 + kj) = s.k0;
  *(bf16x8*)(KhL + (kr + 16) * 136 + kj) = s.k1;
  *(bf16x8*)(KlL + kr * 136 + kj) = s.l0;
  *(bf16x8*)(KlL + (kr + 16) * 136 + kj) = s.l1;
  const int vd = tid >> 2, vj = (tid & 3) * 8;
  *(bf16x8*)(VL + vd * 40 + vj) = s.v0;
  *(bf16x8*)(VL + (vd + 64) * 40 + vj) = s.v1;
}

// Q load + RoPE + hi/lo split. Lane holds row trow, dims c*32 + quad*8 + jj.
// RoPE pairs d (c=0,1) with d+64 (c=2,3); cos/sin only needed for d<64.
__device__ __forceinline__ void load_q_rope(
    const float* __restrict__ qr, const float* __restrict__ cosb,
    const float* __restrict__ sinb, int trow, int quad,
    bf16x8* __restrict__ qh, bf16x8* __restrict__ ql) {
  float u[4][8];
#pragma unroll
  for (int c = 0; c < 4; ++c) {
    *(float4*)&u[c][0] = *(const float4*)(qr + c * 32 + quad * 8);
    *(float4*)&u[c][4] = *(const float4*)(qr + c * 32 + quad * 8 + 4);
  }
  float cv[2][8], sv[2][8];
#pragma unroll
  for (int c = 0; c < 2; ++c) {
    const float* cp = cosb + (size_t)trow * D + c * 32 + quad * 8;
    const float* sp = sinb + (size_t)trow * D + c * 32 + quad * 8;
    *(float4*)&cv[c][0] = *(const float4*)cp;
    *(float4*)&cv[c][4] = *(const float4*)(cp + 4);
    *(float4*)&sv[c][0] = *(const float4*)sp;
    *(float4*)&sv[c][4] = *(const float4*)(sp + 4);
  }
#pragma unroll
  for (int c = 0; c < 4; ++c) {
    const int cc = c & 1;
#pragma unroll
    for (int jj = 0; jj < 8; ++jj) {
      float r = (c < 2) ? (u[c][jj] * cv[cc][jj] - u[c + 2][jj] * sv[cc][jj])
                        : (u[c][jj] * cv[cc][jj] + u[c - 2][jj] * sv[cc][jj]);
      __bf16 hi = (__bf16)r;
      qh[c][jj] = hi;
      ql[c][jj] = (__bf16)(r - (float)hi);
    }
  }
}

__device__ __forceinline__ void softmax_pv(
    floatx4 s0, floatx4 s1,
    const __bf16* __restrict__ VT, __bf16* __restrict__ Pw,
    floatx4* __restrict__ O, float* __restrict__ m_i, float* __restrict__ l_i,
    int j0, int r_base, int n16, int quad) {
  // causal mask (wave-uniform branch; C-layout rows r = r_base + quad*4 + i)
  if (j0 + 31 > r_base) {
#pragma unroll
    for (int i = 0; i < 4; ++i) {
      int r = r_base + quad * 4 + i;
      if (j0 + n16 > r) s0[i] = -INFINITY;
      if (j0 + 16 + n16 > r) s1[i] = -INFINITY;
    }
  }
  float p0[4], p1[4];
#pragma unroll
  for (int i = 0; i < 4; ++i) {
    float mt = fmaxf(s0[i], s1[i]);
    mt = fmaxf(mt, __shfl_xor(mt, 1));
    mt = fmaxf(mt, __shfl_xor(mt, 2));
    mt = fmaxf(mt, __shfl_xor(mt, 4));
    mt = fmaxf(mt, __shfl_xor(mt, 8));
    float mn = fmaxf(m_i[i], mt);
    float alpha = __expf(m_i[i] - mn);   // first tile: exp(-inf)=0
    m_i[i] = mn;
    p0[i] = __expf(s0[i] - mn);
    p1[i] = __expf(s1[i] - mn);
    float rs = p0[i] + p1[i];
    rs += __shfl_xor(rs, 1);
    rs += __shfl_xor(rs, 2);
    rs += __shfl_xor(rs, 4);
    rs += __shfl_xor(rs, 8);
    l_i[i] = l_i[i] * alpha + rs;
#pragma unroll
    for (int dt = 0; dt < 8; ++dt) O[dt][i] *= alpha;
  }
  // P: C-layout -> A-layout via per-wave LDS round-trip (no barrier needed)
#pragma unroll
  for (int i = 0; i < 4; ++i) {
    Pw[(quad * 4 + i) * 40 + n16] = (__bf16)p0[i];
    Pw[(quad * 4 + i) * 40 + n16 + 16] = (__bf16)p1[i];
  }
  bf16x8 pA = *(const bf16x8*)(Pw + n16 * 40 + quad * 8);
#pragma unroll
  for (int dt = 0; dt < 8; ++dt) {
    bf16x8 vB = *(const bf16x8*)(VT + (dt * 16 + n16) * 40 + quad * 8);
    O[dt] = MFMA16(pA, vB, O[dt], 0, 0, 0);
  }
}

template <bool BOTH>
__device__ __forceinline__ void attn_tile2(
    const __bf16* __restrict__ KhT, const __bf16* __restrict__ KlT,
    const __bf16* __restrict__ VT, __bf16* __restrict__ Pw,
    const bf16x8* qh_hi, const bf16x8* ql_hi,
    const bf16x8* qh_lo, const bf16x8* ql_lo,
    floatx4* O_hi, float* m_hi, float* l_hi,
    floatx4* O_lo, float* m_lo, float* l_lo,
    int j0, int rb_hi, int rb_lo, int n16, int quad) {
  floatx4 sh0 = {0.f, 0.f, 0.f, 0.f}, sh1 = {0.f, 0.f, 0.f, 0.f};
  floatx4 sl0 = {0.f, 0.f, 0.f, 0.f}, sl1 = {0.f, 0.f, 0.f, 0.f};
#pragma unroll
  for (int c = 0; c < 4; ++c) {
    const int off = c * 32 + quad * 8;
    bf16x8 k0h = *(const bf16x8*)(KhT + n16 * 136 + off);
    bf16x8 k1h = *(const bf16x8*)(KhT + (n16 + 16) * 136 + off);
    bf16x8 k0l = *(const bf16x8*)(KlT + n16 * 136 + off);
    bf16x8 k1l = *(const bf16x8*)(KlT + (n16 + 16) * 136 + off);
    sh0 = MFMA16(qh_hi[c], k0h, sh0, 0, 0, 0);
    sh0 = MFMA16(ql_hi[c], k0h, sh0, 0, 0, 0);
    sh0 = MFMA16(qh_hi[c], k0l, sh0, 0, 0, 0);
    sh1 = MFMA16(qh_hi[c], k1h, sh1, 0, 0, 0);
    sh1 = MFMA16(ql_hi[c], k1h, sh1, 0, 0, 0);
    sh1 = MFMA16(qh_hi[c], k1l, sh1, 0, 0, 0);
    if (BOTH) {
      sl0 = MFMA16(qh_lo[c], k0h, sl0, 0, 0, 0);
      sl0 = MFMA16(ql_lo[c], k0h, sl0, 0, 0, 0);
      sl0 = MFMA16(qh_lo[c], k0l, sl0, 0, 0, 0);
      sl1 = MFMA16(qh_lo[c], k1h, sl1, 0, 0, 0);
      sl1 = MFMA16(ql_lo[c], k1h, sl1, 0, 0, 0);
      sl1 = MFMA16(qh_lo[c], k1l, sl1, 0, 0, 0);
    }
  }
  softmax_pv(sh0, sh1, VT, Pw, O_hi, m_hi, l_hi, j0, rb_hi, n16, quad);
  if (BOTH) softmax_pv(sl0, sl1, VT, Pw, O_lo, m_lo, l_lo, j0, rb_lo, n16, quad);
}

__global__ __launch_bounds__(256, 2) void flash_attn(
    float* __restrict__ q,
    const __bf16* __restrict__ khi,   // [KVH][T][D]
    const __bf16* __restrict__ klo,   // [KVH][T][D]
    const __bf16* __restrict__ vt,    // [KVH][D][T]
    const float* __restrict__ cosb,
    const float* __restrict__ sinb) {
  __shared__ __attribute__((aligned(16))) __bf16 KhL[2][32 * 136];
  __shared__ __attribute__((aligned(16))) __bf16 KlL[2][32 * 136];
  __shared__ __attribute__((aligned(16))) __bf16 VL[2][128 * 40];
  __shared__ __attribute__((aligned(16))) __bf16 Pst[4][16 * 40];

  const int tid = threadIdx.x;
  const int w = tid >> 6;
  const int lane = tid & 63;
  const int n16 = lane & 15;
  const int quad = lane >> 4;
  const int h = blockIdx.y;
  const int kvh = h >> 2;
  const int p_lo = blockIdx.x;         // 0..15
  const int p_hi = 31 - p_lo;          // 16..31
  const int rb_lo = p_lo * 64 + w * 16;
  const int rb_hi = p_hi * 64 + w * 16;
  const int nt = 64 - 2 * p_lo;              // block-uniform loop count
  const int nt_lo = (rb_lo + 15) / 32 + 1;   // wave-uniform strip bounds
  const int nt_hi = (rb_hi + 15) / 32 + 1;

  const __bf16* Kh = khi + (size_t)kvh * T * D;
  const __bf16* Kl = klo + (size_t)kvh * T * D;
  const __bf16* Vt = vt + (size_t)kvh * D * T;

  // Q fragments (both strips) with fused RoPE
  bf16x8 qh_lo[4], ql_lo[4], qh_hi[4], ql_hi[4];
  load_q_rope(q + (size_t)(rb_lo + n16) * C + h * D, cosb, sinb,
              rb_lo + n16, quad, qh_lo, ql_lo);
  load_q_rope(q + (size_t)(rb_hi + n16) * C + h * D, cosb, sinb,
              rb_hi + n16, quad, qh_hi, ql_hi);

  floatx4 O_lo[8], O_hi[8];
#pragma unroll
  for (int dt = 0; dt < 8; ++dt) {
    O_lo[dt] = (floatx4){0.f, 0.f, 0.f, 0.f};
    O_hi[dt] = (floatx4){0.f, 0.f, 0.f, 0.f};
  }
  float m_lo[4] = {-INFINITY, -INFINITY, -INFINITY, -INFINITY};
  float m_hi[4] = {-INFINITY, -INFINITY, -INFINITY, -INFINITY};
  float l_lo[4] = {0.f, 0.f, 0.f, 0.f};
  float l_hi[4] = {0.f, 0.f, 0.f, 0.f};

  // prologue: stage tile 0 into buffer 0
  StageRegs sreg;
  stage_load(sreg, Kh, Kl, Vt, 0, tid);
  stage_write(sreg, KhL[0], KlL[0], VL[0], tid);
  __syncthreads();

  __bf16* Pw = Pst[w];
  for (int t = 0; t < nt; ++t) {
    const int cur = t & 1;
    const int j0 = t * 32;
    if (t + 1 < nt) stage_load(sreg, Kh, Kl, Vt, j0 + 32, tid);   // issue early
    if (t < nt_hi) {                                              // wave-uniform
      if (t < nt_lo)
        attn_tile2<true>(KhL[cur], KlL[cur], VL[cur], Pw,
                         qh_hi, ql_hi, qh_lo, ql_lo,
                         O_hi, m_hi, l_hi, O_lo, m_lo, l_lo,
                         j0, rb_hi, rb_lo, n16, quad);
      else
        attn_tile2<false>(KhL[cur], KlL[cur], VL[cur], Pw,
                          qh_hi, ql_hi, qh_lo, ql_lo,
                          O_hi, m_hi, l_hi, O_lo, m_lo, l_lo,
                          j0, rb_hi, rb_lo, n16, quad);
    }
    if (t + 1 < nt) stage_write(sreg, KhL[cur ^ 1], KlL[cur ^ 1], VL[cur ^ 1], tid);
    __syncthreads();   // writes visible before next compute; readers of cur done
  }

  // epilogue: y = O / l, overwrite q rows in place (both strips)
#pragma unroll
  for (int i = 0; i < 4; ++i) {
    float inv_l = 1.0f / l_lo[i];
    float inv_h = 1.0f / l_hi[i];
    int r_l = rb_lo + quad * 4 + i;
    int r_h = rb_hi + quad * 4 + i;
    float* yl = q + (size_t)r_l * C + h * D + n16;
    float* yh = q + (size_t)r_h * C + h * D + n16;
#pragma unroll
    for (int dt = 0; dt < 8; ++dt) {
      yl[dt * 16] = O_lo[dt][i] * inv_l;
      yh[dt * 16] = O_hi[dt][i] * inv_h;
    }
  }
}

extern "C" void kernel_launch(void* const* d_in, const int* in_sizes, int n_in,
                              void* d_out, int out_size, void* d_ws, size_t ws_size,
                              hipStream_t stream) {
  (void)in_sizes; (void)n_in; (void)out_size; (void)ws_size;
  const float* x    = (const float*)d_in[0];
  const float* Wq   = (const float*)d_in[1];
  const float* Wk   = (const float*)d_in[2];
  const float* Wv   = (const float*)d_in[3];
  const float* Wo   = (const float*)d_in[4];
  const float* cosb = (const float*)d_in[5];
  const float* sinb = (const float*)d_in[6];
  // d_in[7] = mask: unused (causal structure applied exactly)

  // workspace layout (~44 MB)
  float* q_ws = (float*)d_ws;                         // T*C fp32 (q raw, then y in-place)
  __bf16* khi = (__bf16*)(q_ws + (size_t)T * C);                // 4 MB
  __bf16* klo = khi + (size_t)KVH * T * D;                      // 4 MB
  __bf16* vt  = klo + (size_t)KVH * T * D;                      // 4 MB

  float* out_y = (float*)d_out;
  float* out_k = out_y + (size_t)T * C;
  float* out_v = out_k + (size_t)KVH * T * D;

  dim3 blk(256);
  // fused Q/K/V projections + rope(k) + bf16 conversions, one launch
  gemm_qkv<<<dim3(48, T / 128), blk, 0, stream>>>(
      x, Wq, Wk, Wv, q_ws, out_k, khi, klo, out_v, vt, cosb, sinb);
  // flash attention (RoPE fused into Q load; writes y over q_ws)
  flash_attn<<<dim3(16, H), blk, 0, stream>>>(q_ws, khi, klo, vt, cosb, sinb);
  // output projection: 2-term split (linear path)
  gemm_wo<<<dim3(C / 128, T / 128), blk, 0, stream>>>(q_ws, Wo, out_y);
}